// Round 2
// baseline (145.842 us; speedup 1.0000x reference)
//
#include <hip/hip_runtime.h>
#include <hip/hip_cooperative_groups.h>

namespace cg = cooperative_groups;

// Problem constants (match reference)
#define NXG 2048
#define NYG 2048
// hx = hy = 1/2048 -> 1/h = 2048, 1/(2h) = 1024
__device__ __forceinline__ float inv_h()  { return 2048.0f; }
__device__ __forceinline__ float inv_2h() { return 1024.0f; }

#define BLOCK 256
#define GRID  1024   // 4 blocks/CU on 256 CUs -> fully co-resident for coop launch

// Single cooperative kernel:
//  Phase 1: grid-stride over float4 chunks, accumulate vx^2+vy^2, block-reduce
//           into partial[blockIdx.x] (d_ws scratch).
//  grid.sync()
//  Phase 2: block 0 reduces the GRID partials and writes 0.5*sum to out[0].
__global__ __launch_bounds__(BLOCK) void
energy_kernel(const float* __restrict__ phi, float* __restrict__ partial,
              float* __restrict__ out) {
    cg::grid_group grid = cg::this_grid();

    const int totalChunks = (NXG * NYG) / 4;  // 1,048,576
    float acc = 0.0f;

    for (int c = blockIdx.x * blockDim.x + threadIdx.x;
         c < totalChunks;
         c += gridDim.x * blockDim.x) {
        const int i  = c >> 9;            // c / (NYG/4 = 512)
        const int j4 = (c & 511) << 2;    // starting y index of this chunk
        const float* row = phi + (size_t)i * NYG;

        const float4 self = *(const float4*)(row + j4);

        // x-direction: clamped neighbor rows + edge scale
        const int im1 = (i > 0)        ? i - 1 : 0;
        const int ip1 = (i < NXG - 1)  ? i + 1 : NXG - 1;
        const float sx = (i == 0 || i == NXG - 1) ? inv_h() : inv_2h();
        const float4 up = *(const float4*)(phi + (size_t)im1 * NYG + j4);
        const float4 dn = *(const float4*)(phi + (size_t)ip1 * NYG + j4);

        const float vx0 = (dn.x - up.x) * sx;
        const float vx1 = (dn.y - up.y) * sx;
        const float vx2 = (dn.z - up.z) * sx;
        const float vx3 = (dn.w - up.w) * sx;

        // y-direction within the row
        float vy0, vy1, vy2, vy3;
        if (j4 == 0) {
            vy0 = (self.y - self.x) * inv_h();      // forward diff at y=0
        } else {
            const float left = row[j4 - 1];
            vy0 = (self.y - left) * inv_2h();
        }
        vy1 = (self.z - self.x) * inv_2h();
        vy2 = (self.w - self.y) * inv_2h();
        if (j4 + 4 == NYG) {
            vy3 = (self.w - self.z) * inv_h();      // backward diff at y=ny-1
        } else {
            const float right = row[j4 + 4];
            vy3 = (right - self.z) * inv_2h();
        }

        acc += vx0 * vx0 + vx1 * vx1 + vx2 * vx2 + vx3 * vx3
             + vy0 * vy0 + vy1 * vy1 + vy2 * vy2 + vy3 * vy3;
    }

    // wave (64-lane) shuffle reduction
    #pragma unroll
    for (int off = 32; off > 0; off >>= 1)
        acc += __shfl_down(acc, off, 64);

    __shared__ float smem[BLOCK / 64];
    const int lane = threadIdx.x & 63;
    const int wave = threadIdx.x >> 6;
    if (lane == 0) smem[wave] = acc;
    __syncthreads();
    if (threadIdx.x == 0) {
        float s = 0.0f;
        #pragma unroll
        for (int w = 0; w < BLOCK / 64; ++w) s += smem[w];
        partial[blockIdx.x] = s;
    }

    grid.sync();

    // Phase 2: block 0 reduces GRID partials.
    if (blockIdx.x == 0) {
        float a2 = 0.0f;
        for (int idx = threadIdx.x; idx < GRID; idx += BLOCK)
            a2 += partial[idx];

        #pragma unroll
        for (int off = 32; off > 0; off >>= 1)
            a2 += __shfl_down(a2, off, 64);

        __shared__ float smem2[BLOCK / 64];
        if (lane == 0) smem2[wave] = a2;
        __syncthreads();
        if (threadIdx.x == 0) {
            float s = 0.0f;
            #pragma unroll
            for (int w = 0; w < BLOCK / 64; ++w) s += smem2[w];
            out[0] = 0.5f * s;
        }
    }
}

extern "C" void kernel_launch(void* const* d_in, const int* in_sizes, int n_in,
                              void* d_out, int out_size, void* d_ws, size_t ws_size,
                              hipStream_t stream) {
    // d_in[0] = pos (unused by the reference), d_in[1] = potential_field [2048*2048] f32
    const float* phi = (const float*)d_in[1];
    float* out = (float*)d_out;
    float* partial = (float*)d_ws;  // GRID floats of scratch

    void* args[] = {(void*)&phi, (void*)&partial, (void*)&out};
    hipLaunchCooperativeKernel((const void*)energy_kernel, dim3(GRID), dim3(BLOCK),
                               args, 0, stream);
}

// Round 3
// 73.556 us; speedup vs baseline: 1.9827x; 1.9827x over previous
//
#include <hip/hip_runtime.h>

// Problem constants (match reference)
#define NXG 2048
#define NYG 2048
// hx = hy = 1/2048 -> 1/h = 2048, 1/(2h) = 1024
__device__ __forceinline__ float inv_h()  { return 2048.0f; }
__device__ __forceinline__ float inv_2h() { return 1024.0f; }

#define BLOCK 256
#define GRID  1024

// Kernel 1: each thread processes a ROW-PAIR x float4 chunk: rows (2p, 2p+1),
// cols j4..j4+3. The x-stencil needs rows 2p-1..2p+2 -> 4 float4 loads for
// 2 output rows (2 loads/row vs 3 in the naive version), cutting cross-XCD
// HBM overfetch. y-edge scalars hit L1 (same cache lines as the float4s).
__global__ __launch_bounds__(BLOCK) void
energy_partial_kernel(const float* __restrict__ phi, float* __restrict__ partial) {
    const int totalChunks = (NXG / 2) * (NYG / 4);  // 1024 * 512 = 524,288
    float acc = 0.0f;

    for (int c = blockIdx.x * blockDim.x + threadIdx.x;
         c < totalChunks;
         c += gridDim.x * blockDim.x) {
        const int p  = c >> 9;            // pair index 0..1023
        const int j4 = (c & 511) << 2;    // starting y index of this chunk
        const int i0 = 2 * p;             // first row of pair  (never 2047)
        const int i1 = i0 + 1;            // second row of pair (never 0)

        const int rm = (p > 0)            ? i0 - 1 : 0;        // clamp top
        const int rp = (p < NXG / 2 - 1)  ? i1 + 1 : NXG - 1;  // clamp bottom
        const float sx0 = (i0 == 0)       ? inv_h() : inv_2h();
        const float sx1 = (i1 == NXG - 1) ? inv_h() : inv_2h();

        const float* rowm = phi + (size_t)rm * NYG;
        const float* row0 = phi + (size_t)i0 * NYG;
        const float* row1 = phi + (size_t)i1 * NYG;
        const float* rowp = phi + (size_t)rp * NYG;

        const float4 a = *(const float4*)(rowm + j4);
        const float4 b = *(const float4*)(row0 + j4);
        const float4 g = *(const float4*)(row1 + j4);
        const float4 d = *(const float4*)(rowp + j4);

        // x-direction velocities
        const float vxa0 = (g.x - a.x) * sx0, vxa1 = (g.y - a.y) * sx0;
        const float vxa2 = (g.z - a.z) * sx0, vxa3 = (g.w - a.w) * sx0;
        const float vxb0 = (d.x - b.x) * sx1, vxb1 = (d.y - b.y) * sx1;
        const float vxb2 = (d.z - b.z) * sx1, vxb3 = (d.w - b.w) * sx1;

        // y-direction velocities, row0 (from b) and row1 (from g)
        float vya0, vya3, vyb0, vyb3;
        if (j4 == 0) {
            vya0 = (b.y - b.x) * inv_h();
            vyb0 = (g.y - g.x) * inv_h();
        } else {
            vya0 = (b.y - row0[j4 - 1]) * inv_2h();
            vyb0 = (g.y - row1[j4 - 1]) * inv_2h();
        }
        const float vya1 = (b.z - b.x) * inv_2h();
        const float vya2 = (b.w - b.y) * inv_2h();
        const float vyb1 = (g.z - g.x) * inv_2h();
        const float vyb2 = (g.w - g.y) * inv_2h();
        if (j4 + 4 == NYG) {
            vya3 = (b.w - b.z) * inv_h();
            vyb3 = (g.w - g.z) * inv_h();
        } else {
            vya3 = (row0[j4 + 4] - b.z) * inv_2h();
            vyb3 = (row1[j4 + 4] - g.z) * inv_2h();
        }

        acc += vxa0 * vxa0 + vxa1 * vxa1 + vxa2 * vxa2 + vxa3 * vxa3
             + vxb0 * vxb0 + vxb1 * vxb1 + vxb2 * vxb2 + vxb3 * vxb3
             + vya0 * vya0 + vya1 * vya1 + vya2 * vya2 + vya3 * vya3
             + vyb0 * vyb0 + vyb1 * vyb1 + vyb2 * vyb2 + vyb3 * vyb3;
    }

    // wave (64-lane) shuffle reduction
    #pragma unroll
    for (int off = 32; off > 0; off >>= 1)
        acc += __shfl_down(acc, off, 64);

    __shared__ float smem[BLOCK / 64];
    const int lane = threadIdx.x & 63;
    const int wave = threadIdx.x >> 6;
    if (lane == 0) smem[wave] = acc;
    __syncthreads();
    if (threadIdx.x == 0) {
        float s = 0.0f;
        #pragma unroll
        for (int w = 0; w < BLOCK / 64; ++w) s += smem[w];
        partial[blockIdx.x] = s;
    }
}

// Kernel 2: single block reduces GRID partials, writes 0.5 * sum.
__global__ __launch_bounds__(BLOCK) void
energy_finalize_kernel(const float* __restrict__ partial, float* __restrict__ out) {
    float acc = 0.0f;
    for (int idx = threadIdx.x; idx < GRID; idx += BLOCK)
        acc += partial[idx];

    #pragma unroll
    for (int off = 32; off > 0; off >>= 1)
        acc += __shfl_down(acc, off, 64);

    __shared__ float smem[BLOCK / 64];
    const int lane = threadIdx.x & 63;
    const int wave = threadIdx.x >> 6;
    if (lane == 0) smem[wave] = acc;
    __syncthreads();
    if (threadIdx.x == 0) {
        float s = 0.0f;
        #pragma unroll
        for (int w = 0; w < BLOCK / 64; ++w) s += smem[w];
        out[0] = 0.5f * s;
    }
}

extern "C" void kernel_launch(void* const* d_in, const int* in_sizes, int n_in,
                              void* d_out, int out_size, void* d_ws, size_t ws_size,
                              hipStream_t stream) {
    // d_in[0] = pos (unused by the reference), d_in[1] = potential_field [2048*2048] f32
    const float* phi = (const float*)d_in[1];
    float* out = (float*)d_out;
    float* partial = (float*)d_ws;  // GRID floats of scratch

    energy_partial_kernel<<<GRID, BLOCK, 0, stream>>>(phi, partial);
    energy_finalize_kernel<<<1, BLOCK, 0, stream>>>(partial, out);
}